// Round 6
// baseline (189.525 us; speedup 1.0000x reference)
//
#include <hip/hip_runtime.h>
#include <hip/hip_bf16.h>

// MHA: B=4, N=1024, E=1024, H=16, d=64.  fp32 I/O, bf16 MFMA internals.
//
// Round 18: gemm_qkv9 = deep-pipelined 256x192 tile, grid 256 (1 block/CU,
// ALL CUs busy), 512 thr (8 waves 2Mx4N, per-wave 128x48, acc[8][3]).
// A dbuf (2x32K) + B ring-3 (3x24K) = 136 KB dynamic LDS.  4 phases/K-step:
// {7 ds_read_b128, 2 glds issues, s_barrier, 12 MFMA (setprio), s_barrier}.
// Counted vmcnt(3) at每 K-step top (never 0 until tail): issue order per iter
// T = A(T+1) then B(T+2), so newest-3 = B(T+1); A(T)/B(T) drained.  128-B
// LDS rows keep the r13 conflict-free XOR swizzle (r16's 64-B rows caused
// 2.36M conflicts).  B tiles straddle z (192 % 1024): per-row z-select in
// staging, per-frag z-select in epilogue.  attn/gemm_out/cvt = r17 (ring-3
// counted vmcnt).  Old 128x128 qkv kept as small-ws fp32 fallback.
//
// XOR-swizzled [row][64] LDS tiles: LDS[row][c8] holds G[row][c8 ^ (row&7)];
// frag readers XOR with l15&7.  Staging via global_load_lds(16B).
//
// ws (40 MB fast path): [Qw 8M][Kw 8M][Vw 8M][xb/Ow 8M][Wqb][Wkb][Wvb][Wob]
// (2 MB each).  ws_size < 40 MB -> fp32-W fallback (deterministic branch).
//
// MFMA m89/m91 layouts: A-frag A[m=l&15][k=(l>>4)*8+j]; B-frag same addressing
// from row-major [n][k]; C/D col=l&15, row=(l>>4)*4+reg.

typedef __bf16 bf16x8 __attribute__((ext_vector_type(8)));
typedef __bf16 bf16x4 __attribute__((ext_vector_type(4)));
typedef float  f32x4  __attribute__((ext_vector_type(4)));

#define LOG2E 1.44269504f

__device__ __forceinline__ void glds16(const __bf16* g, __bf16* l) {
  __builtin_amdgcn_global_load_lds(
      (const __attribute__((address_space(1))) void*)g,
      (__attribute__((address_space(3))) void*)l, 16, 0, 0);
}

__global__ __launch_bounds__(256) void cvt_f32_bf16(const float* __restrict__ in,
                                                    __bf16* __restrict__ out, int n4) {
  int i = blockIdx.x * 256 + threadIdx.x;
  if (i < n4) {
    float4 v = *(const float4*)(in + (size_t)i * 4);
    bf16x4 b = {(__bf16)v.x, (__bf16)v.y, (__bf16)v.z, (__bf16)v.w};
    *(bf16x4*)(out + (size_t)i * 4) = b;
  }
}

// Fused conversion: x (1M float4) + Wq/Wk/Wv/Wo (256K float4 each).
__global__ __launch_bounds__(256) void cvt_all(const float* __restrict__ x,
                                               const float* __restrict__ Wq,
                                               const float* __restrict__ Wk,
                                               const float* __restrict__ Wv,
                                               const float* __restrict__ Wo,
                                               __bf16* __restrict__ xb,
                                               __bf16* __restrict__ Wqb,
                                               __bf16* __restrict__ Wkb,
                                               __bf16* __restrict__ Wvb,
                                               __bf16* __restrict__ Wob) {
  const int i = blockIdx.x * 256 + threadIdx.x;  // 0..2097151
  const float* src;
  __bf16* dst;
  int off;
  if (i < 1048576) {
    src = x; dst = xb; off = i;
  } else {
    const int j = i - 1048576;
    const int seg = j >> 18;  // 0..3
    off = j & 262143;
    src = (seg == 0) ? Wq : (seg == 1) ? Wk : (seg == 2) ? Wv : Wo;
    dst = (seg == 0) ? Wqb : (seg == 1) ? Wkb : (seg == 2) ? Wvb : Wob;
  }
  float4 v = *(const float4*)(src + (size_t)off * 4);
  bf16x4 b = {(__bf16)v.x, (__bf16)v.y, (__bf16)v.z, (__bf16)v.w};
  *(bf16x4*)(dst + (size_t)off * 4) = b;
}

// ---------------------------------------------------------------------------
// gemm_qkv9: fused QKV projection, deep-pipelined 256x192 tile.
// C[4096, 3072] = x @ [Wq;Wk;Wv]^T.  Grid 256 = 16m x 16n (1 block/CU).
// XCD map: c=bid&7 owns mb {2c, 2c+1}; nb = (bid>>3)>>1.
// Per K-step T (BK=64): 4 phases p=(s,mh); phase = {af[4]+bf[3] ds_read,
// 2 glds stage issues, s_barrier, 12 MFMA, s_barrier}.  vmcnt(3) at iter top.
// Stage stream: iter T issues A(T+1) chunks (p0,p1) then B(T+2) (p2,p3).
// A dbuf slot = T&1 (32 KB); B ring slot = T%3 (24 KB).
// ---------------------------------------------------------------------------
__global__ __launch_bounds__(512, 2) void gemm_qkv9(const __bf16* __restrict__ A,
                                                    const __bf16* __restrict__ Wqp,
                                                    const __bf16* __restrict__ Wkp,
                                                    const __bf16* __restrict__ Wvp,
                                                    const float* __restrict__ bq,
                                                    const float* __restrict__ bk,
                                                    const float* __restrict__ bv,
                                                    __bf16* __restrict__ Qw,
                                                    __bf16* __restrict__ Kw,
                                                    __bf16* __restrict__ Vw) {
  extern __shared__ __attribute__((aligned(16))) __bf16 lds[];
  // A slots: lds + (T&1)*16384   ([256][64] = 32 KB each)
  // B slots: lds + 32768 + (T%3)*12288  ([192][64] = 24 KB each)

  const int tid = threadIdx.x;
  const int lane = tid & 63;
  const int w = tid >> 6, wm = w >> 2, wn = w & 3;
  const int l15 = lane & 15, lq = lane >> 4;
  const int xs = l15 & 7;
  const int srow = tid >> 3;            // 0..63 (staging row within chunk)
  const int scol = tid & 7;             // 16B col chunk
  const int sxor = (scol ^ (srow & 7)) * 8;

  const int bid = blockIdx.x;
  const int c = bid & 7, t = bid >> 3;  // t 0..31
  const int mb = c * 2 + (t & 1);       // 0..15
  const int nb = t >> 1;                // 0..15
  const int m0 = mb * 256;
  const int n0g = nb * 192;

  auto stageA = [&](int T, int chunk) {
    const int row = chunk * 64 + srow;
    glds16(A + (size_t)(m0 + row) * 1024 + T * 64 + sxor,
           lds + (T & 1) * 16384 + row * 64 + scol * 8);
  };
  auto stageB = [&](int T, int chunk) {
    const int row = chunk * 64 + srow;  // 0..191
    const int g = n0g + row;
    const int z = g >> 10;
    const __bf16* W = (z == 0) ? Wqp : (z == 1) ? Wkp : Wvp;
    glds16(W + (size_t)(g & 1023) * 1024 + T * 64 + sxor,
           lds + 32768 + (T % 3) * 12288 + row * 64 + scol * 8);
  };

  f32x4 acc[8][3] = {};

  // prologue: B(0) x3, A(0) x4, B(1) x3  (order matters for vmcnt)
#pragma unroll
  for (int ch = 0; ch < 3; ++ch) stageB(0, ch);
#pragma unroll
  for (int ch = 0; ch < 4; ++ch) stageA(0, ch);
#pragma unroll
  for (int ch = 0; ch < 3; ++ch) stageB(1, ch);

  for (int T = 0; T < 16; ++T) {
    // A(T), B(T) landed; newest 3 (B(T+1)) stay in flight
    if (T < 15)
      asm volatile("s_waitcnt vmcnt(3)" ::: "memory");
    else
      asm volatile("s_waitcnt vmcnt(0)" ::: "memory");
    __builtin_amdgcn_s_barrier();

    const __bf16* Ab = lds + (T & 1) * 16384 + (wm * 128) * 64;
    const __bf16* Bb = lds + 32768 + (T % 3) * 12288 + (wn * 48) * 64;

#pragma unroll
    for (int p = 0; p < 4; ++p) {
      const int s = p >> 1, mh = p & 1;
      const int kc = ((s * 4 + lq) ^ xs) * 8;
      bf16x8 af[4], bf[3];
#pragma unroll
      for (int mt = 0; mt < 4; ++mt)
        af[mt] = *(const bf16x8*)(Ab + (mh * 64 + mt * 16 + l15) * 64 + kc);
#pragma unroll
      for (int nt = 0; nt < 3; ++nt)
        bf[nt] = *(const bf16x8*)(Bb + (nt * 16 + l15) * 64 + kc);

      if (T < 15) {
        if (p == 0)      { stageA(T + 1, 0); stageA(T + 1, 1); }
        else if (p == 1) { stageA(T + 1, 2); stageA(T + 1, 3); }
        else if (T < 14) {
          if (p == 2)    { stageB(T + 2, 0); stageB(T + 2, 1); }
          else           { stageB(T + 2, 2); }
        }
      }

      __builtin_amdgcn_s_barrier();
      __builtin_amdgcn_s_setprio(1);
#pragma unroll
      for (int mt = 0; mt < 4; ++mt)
#pragma unroll
        for (int nt = 0; nt < 3; ++nt)
          acc[mh * 4 + mt][nt] = __builtin_amdgcn_mfma_f32_16x16x32_bf16(
              af[mt], bf[nt], acc[mh * 4 + mt][nt], 0, 0, 0);
      __builtin_amdgcn_s_setprio(0);
      __builtin_amdgcn_s_barrier();
    }
  }

  // epilogue: per-frag z select (192-wide tiles straddle Q/K/V boundaries)
#pragma unroll
  for (int mt = 0; mt < 8; ++mt) {
    const int mg_base = m0 + wm * 128 + mt * 16 + lq * 4;
    const int bb = mg_base >> 10, nr0 = mg_base & 1023;
#pragma unroll
    for (int nt = 0; nt < 3; ++nt) {
      const int ng = n0g + wn * 48 + nt * 16 + l15;
      const int z = ng >> 10, nl = ng & 1023;
      const float* bias = (z == 0) ? bq : (z == 1) ? bk : bv;
      __bf16* C = (z == 0) ? Qw : (z == 1) ? Kw : Vw;
      const float scale = (z == 0) ? LOG2E : 1.0f;
      const float bv4 = bias[nl];
      const int h = nl >> 6, dd = nl & 63;
      if (z != 2) {
#pragma unroll
        for (int rr = 0; rr < 4; ++rr) {
          const int mg = mg_base + rr;
          const size_t idx =
              ((size_t)(bb * 16 + h) << 16) + (size_t)(mg & 1023) * 64 + dd;
          C[idx] = (__bf16)((acc[mt][nt][rr] + bv4) * scale);
        }
      } else {
        bf16x4 o4 = {(__bf16)(acc[mt][nt][0] + bv4), (__bf16)(acc[mt][nt][1] + bv4),
                     (__bf16)(acc[mt][nt][2] + bv4), (__bf16)(acc[mt][nt][3] + bv4)};
        *(bf16x4*)(&C[((size_t)(bb * 16 + h) << 16) + (size_t)dd * 1024 + nr0]) = o4;
      }
    }
  }
}

// ---------------------------------------------------------------------------
// Fallback QKV (small-ws): 128x128 tile, BK=64, grid 768.  fp32-W path.
// ---------------------------------------------------------------------------
template <bool WBF16>
__global__ __launch_bounds__(256, 3) void gemm_qkv(const __bf16* __restrict__ A,
                                                   const void* __restrict__ Wqp,
                                                   const void* __restrict__ Wkp,
                                                   const void* __restrict__ Wvp,
                                                   const float* __restrict__ bq,
                                                   const float* __restrict__ bk,
                                                   const float* __restrict__ bv,
                                                   __bf16* __restrict__ Qw,
                                                   __bf16* __restrict__ Kw,
                                                   __bf16* __restrict__ Vw) {
  constexpr int BST = WBF16 ? 64 : 72;
  __shared__ __attribute__((aligned(16))) __bf16 As[128][64];
  __shared__ __attribute__((aligned(16))) __bf16 Bs[128 * BST];

  const int tid = threadIdx.x;
  const int lane = tid & 63, w = tid >> 6;
  const int wm = w >> 1, wn = w & 1;
  const int l15 = lane & 15, lq = lane >> 4;
  const int lr = lane >> 3, lc = lane & 7;
  const int xs = l15 & 7;

  const int bid = blockIdx.x;
  const int c = bid & 7, t = bid >> 3;
  const int z = t >> 5;
  const int r = t & 31;
  const int nb = r & 7;
  const int mb = c * 4 + (r >> 3);
  const int m0 = mb * 128, n0 = nb * 128;

  const void* Wp = (z == 0) ? Wqp : (z == 1) ? Wkp : Wvp;
  const float* bias = (z == 0) ? bq : (z == 1) ? bk : bv;
  __bf16* C = (z == 0) ? Qw : (z == 1) ? Kw : Vw;
  const float scale = (z == 0) ? LOG2E : 1.0f;

  f32x4 acc[4][4] = {};

  for (int k0 = 0; k0 < 1024; k0 += 64) {
#pragma unroll
    for (int i = 0; i < 4; ++i) {
      const int row = w * 32 + i * 8 + lr;
      glds16(A + (size_t)(m0 + row) * 1024 + k0 + ((lc ^ lr) * 8), &As[row][lc * 8]);
    }
    if (WBF16) {
      const __bf16* Wb = (const __bf16*)Wp;
#pragma unroll
      for (int i = 0; i < 4; ++i) {
        const int row = w * 32 + i * 8 + lr;
        glds16(Wb + (size_t)(n0 + row) * 1024 + k0 + ((lc ^ lr) * 8), &Bs[row * 64 + lc * 8]);
      }
    } else {
      const float* W = (const float*)Wp;
#pragma unroll
      for (int i = 0; i < 8; ++i) {
        const int cc = i * 256 + tid, row = cc >> 4, col = (cc & 15) * 4;
        float4 wv = *(const float4*)(W + (size_t)(n0 + row) * 1024 + k0 + col);
        bf16x4 b4 = {(__bf16)wv.x, (__bf16)wv.y, (__bf16)wv.z, (__bf16)wv.w};
        *(bf16x4*)(&Bs[row * 72 + col]) = b4;
      }
    }
    __syncthreads();
#pragma unroll
    for (int s = 0; s < 2; ++s) {
      bf16x8 af[4], bfv[4];
#pragma unroll
      for (int mt = 0; mt < 4; ++mt)
        af[mt] = *(const bf16x8*)(&As[wm * 64 + mt * 16 + l15][((s * 4 + lq) ^ xs) * 8]);
#pragma unroll
      for (int nt = 0; nt < 4; ++nt) {
        const int row = wn * 64 + nt * 16 + l15;
        if (WBF16)
          bfv[nt] = *(const bf16x8*)(&Bs[row * 64 + (((s * 4 + lq) ^ xs) * 8)]);
        else
          bfv[nt] = *(const bf16x8*)(&Bs[row * 72 + s * 32 + lq * 8]);
      }
#pragma unroll
      for (int mt = 0; mt < 4; ++mt)
#pragma unroll
        for (int nt = 0; nt < 4; ++nt)
          acc[mt][nt] = __builtin_amdgcn_mfma_f32_16x16x32_bf16(
              af[mt], bfv[nt], acc[mt][nt], 0, 0, 0);
    }
    __syncthreads();
  }

#pragma unroll
  for (int mt = 0; mt < 4; ++mt) {
    const int mg_base = m0 + wm * 64 + mt * 16 + lq * 4;
    const int bb = mg_base >> 10, nr0 = mg_base & 1023;
#pragma unroll
    for (int nt = 0; nt < 4; ++nt) {
      const int ng = n0 + wn * 64 + nt * 16 + l15;
      const float bv = bias[ng];
      const int h = ng >> 6, dd = ng & 63;
      if (z != 2) {
#pragma unroll
        for (int rr = 0; rr < 4; ++rr) {
          const int mg = mg_base + rr;
          const size_t idx =
              ((size_t)(bb * 16 + h) << 16) + (size_t)(mg & 1023) * 64 + dd;
          C[idx] = (__bf16)((acc[mt][nt][rr] + bv) * scale);
        }
      } else {
        bf16x4 o4 = {(__bf16)(acc[mt][nt][0] + bv), (__bf16)(acc[mt][nt][1] + bv),
                     (__bf16)(acc[mt][nt][2] + bv), (__bf16)(acc[mt][nt][3] + bv)};
        *(bf16x4*)(&C[((size_t)(bb * 16 + h) << 16) + (size_t)dd * 1024 + nr0]) = o4;
      }
    }
  }
}

// ---------------------------------------------------------------------------
// Out projection: out[4096,1024] fp32 = O @ Wo^T + bo.  64x128 tile, BK=64,
// 1D grid 512, XCD-mapped.  Ring-3 prefetch-distance-2, counted vmcnt (r17).
// ---------------------------------------------------------------------------
__global__ __launch_bounds__(256, 2) void gemm_out(const __bf16* __restrict__ A,
                                                   const __bf16* __restrict__ W,
                                                   const float* __restrict__ bias,
                                                   float* __restrict__ C) {
  extern __shared__ __attribute__((aligned(16))) __bf16 lds_o[];
  __bf16(*As)[64][64] = (__bf16(*)[64][64])lds_o;              // 3 x 4096
  __bf16(*Bs)[128][64] = (__bf16(*)[128][64])(lds_o + 12288);  // 3 x 8192

  const int tid = threadIdx.x;
  const int lane = tid & 63, w = tid >> 6;
  const int wm = w >> 1, wn = w & 1;
  const int l15 = lane & 15, lq = lane >> 4;
  const int lr = lane >> 3, lc = lane & 7;
  const int xs = l15 & 7;

  const int bid = blockIdx.x;
  const int c = bid & 7, t = bid >> 3;  // c = XCD, t = 0..63
  const int mb = c * 8 + (t & 7);       // 0..63
  const int nb = t >> 3;                // 0..7
  const int m0 = mb * 64, n0 = nb * 128;

  auto stage = [&](int kb, int sl) {
    const int k0 = kb * 64;
#pragma unroll
    for (int i = 0; i < 2; ++i) {  // A: wave w rows w*16..+15
      const int row = w * 16 + i * 8 + lr;
      glds16(A + (size_t)(m0 + row) * 1024 + k0 + ((lc ^ lr) * 8), &As[sl][row][lc * 8]);
    }
#pragma unroll
    for (int i = 0; i < 4; ++i) {  // B: wave w rows w*32..+31
      const int row = w * 32 + i * 8 + lr;
      glds16(W + (size_t)(n0 + row) * 1024 + k0 + ((lc ^ lr) * 8), &Bs[sl][row][lc * 8]);
    }
  };

  f32x4 acc[2][4] = {};

  stage(0, 0);
  stage(1, 1);

  for (int kb = 0; kb < 16; ++kb) {
    if (kb < 15)
      asm volatile("s_waitcnt vmcnt(6)" ::: "memory");
    else
      asm volatile("s_waitcnt vmcnt(0)" ::: "memory");
    __builtin_amdgcn_s_barrier();
    if (kb < 14) stage(kb + 2, (kb + 2) % 3);

    const int sl = kb % 3;
#pragma unroll
    for (int s = 0; s < 2; ++s) {
      bf16x8 af[2], bfv[4];
#pragma unroll
      for (int mt = 0; mt < 2; ++mt)
        af[mt] = *(const bf16x8*)(&As[sl][wm * 32 + mt * 16 + l15][((s * 4 + lq) ^ xs) * 8]);
#pragma unroll
      for (int nt = 0; nt < 4; ++nt)
        bfv[nt] = *(const bf16x8*)(&Bs[sl][wn * 64 + nt * 16 + l15][((s * 4 + lq) ^ xs) * 8]);
      __builtin_amdgcn_s_setprio(1);
#pragma unroll
      for (int mt = 0; mt < 2; ++mt)
#pragma unroll
        for (int nt = 0; nt < 4; ++nt)
          acc[mt][nt] = __builtin_amdgcn_mfma_f32_16x16x32_bf16(
              af[mt], bfv[nt], acc[mt][nt], 0, 0, 0);
      __builtin_amdgcn_s_setprio(0);
    }
  }

#pragma unroll
  for (int mt = 0; mt < 2; ++mt) {
    const int mg_base = m0 + wm * 32 + mt * 16 + lq * 4;
#pragma unroll
    for (int nt = 0; nt < 4; ++nt) {
      const int ng = n0 + wn * 64 + nt * 16 + l15;
      const float bv = bias[ng];
#pragma unroll
      for (int r = 0; r < 4; ++r)
        C[(size_t)(mg_base + r) * 1024 + ng] = acc[mt][nt][r] + bv;
    }
  }
}

// ---------------------------------------------------------------------------
// Flash attention (r17 structure): 32 q/wave, 128 q/block, grid (64,8).
// Ring-3 prefetch-distance-2 K/V, counted vmcnt(4).  Q frags register-hoisted;
// Q-stage LDS reused as P buffer.  exp2 softmax (Q pre-scaled by log2e).
// Reference divides by sqrt(E)=32 AFTER softmax -> /(l*32).  66 KB dynamic.
// ---------------------------------------------------------------------------
__global__ __launch_bounds__(256, 2) void attn_kernel(const __bf16* __restrict__ Q,
                                                      const __bf16* __restrict__ K,
                                                      const __bf16* __restrict__ Vt,
                                                      __bf16* __restrict__ O) {
  extern __shared__ __attribute__((aligned(16))) __bf16 lds_a[];
  __bf16(*Ks)[64][64] = (__bf16(*)[64][64])lds_a;               // 3 x 4096
  __bf16(*Vs)[64][64] = (__bf16(*)[64][64])(lds_a + 12288);     // 3 x 4096
  __bf16* PQ = lds_a + 24576;                                   // 9216 elems
  __bf16(*Qst)[64] = (__bf16(*)[64])PQ;                         // [128][64]
  __bf16(*Ps)[32][72] = (__bf16(*)[32][72])PQ;                  // [4][32][72]

  const int tid = threadIdx.x;
  const int lane = tid & 63, w = tid >> 6;
  const int l15 = lane & 15, lq = lane >> 4;
  const int lr = lane >> 3, lc = lane & 7;
  const int xs = l15 & 7;

  const int bh = blockIdx.x;  // 0..63  (same-head blocks share an XCD)
  const int qt = blockIdx.y;  // 0..7
  const __bf16* Qh = Q + (size_t)bh * 65536;
  const __bf16* Kh = K + (size_t)bh * 65536;
  const __bf16* Vh = Vt + (size_t)bh * 65536;

  auto stage_kv = [&](int kb, int sl) {
#pragma unroll
    for (int i = 0; i < 2; ++i) {
      const int row = w * 16 + i * 8 + lr;
      glds16(Kh + (size_t)kb * 4096 + (size_t)row * 64 + ((lc ^ lr) * 8),
             &Ks[sl][row][lc * 8]);
      glds16(Vh + (size_t)row * 1024 + kb * 64 + ((lc ^ lr) * 8),
             &Vs[sl][row][lc * 8]);
    }
  };

  // prologue: stage Q tile (128x64) + K/V slot 0
#pragma unroll
  for (int i = 0; i < 4; ++i) {
    const int row = w * 32 + i * 8 + lr;
    glds16(Qh + (size_t)(qt * 128 + row) * 64 + ((lc ^ lr) * 8), &Qst[row][lc * 8]);
  }
  stage_kv(0, 0);
  __syncthreads();  // drain Q + slot0 glds for all waves
  bf16x8 bqr[2][2];  // [nq][s]
#pragma unroll
  for (int nq = 0; nq < 2; ++nq)
#pragma unroll
    for (int s = 0; s < 2; ++s)
      bqr[nq][s] = *(const bf16x8*)(&Qst[w * 32 + nq * 16 + l15][((s * 4 + lq) ^ xs) * 8]);
  __syncthreads();  // all waves done reading Qst before PQ reused as Ps
  stage_kv(1, 1);   // distance-2 pipeline primed (4 loads in flight)

  float l_run[2] = {0.0f, 0.0f};
  f32x4 oacc[2][4] = {};

  for (int kb = 0; kb < 16; ++kb) {
    if (kb < 15)
      asm volatile("s_waitcnt vmcnt(4)" ::: "memory");
    else
      asm volatile("s_waitcnt vmcnt(0)" ::: "memory");
    __builtin_amdgcn_s_barrier();
    if (kb < 14) stage_kv(kb + 2, (kb + 2) % 3);
    const int sl = kb % 3;

    // S^T: rows = kseq(64), cols = this wave's 32 q (2 frags of 16)
    f32x4 sacc[2][4] = {};
    __builtin_amdgcn_s_setprio(1);
#pragma unroll
    for (int s = 0; s < 2; ++s) {
#pragma unroll
      for (int mt = 0; mt < 4; ++mt) {
        bf16x8 ak = *(const bf16x8*)(&Ks[sl][mt * 16 + l15][((s * 4 + lq) ^ xs) * 8]);
#pragma unroll
        for (int nq = 0; nq < 2; ++nq)
          sacc[nq][mt] = __builtin_amdgcn_mfma_f32_16x16x32_bf16(
              ak, bqr[nq][s], sacc[nq][mt], 0, 0, 0);
      }
    }
    __builtin_amdgcn_s_setprio(0);

    // softmax numerator via exp2 (per-lane q = w*32 + nq*16 + l15)
#pragma unroll
    for (int nq = 0; nq < 2; ++nq) {
      float sum = 0.0f;
#pragma unroll
      for (int mt = 0; mt < 4; ++mt)
#pragma unroll
        for (int r = 0; r < 4; ++r) {
          const float e = __builtin_amdgcn_exp2f(sacc[nq][mt][r]);
          sacc[nq][mt][r] = e;
          sum += e;
        }
      sum += __shfl_xor(sum, 16, 64);
      sum += __shfl_xor(sum, 32, 64);
      l_run[nq] += sum;
    }

    // P -> LDS row-major [q][k] (padded), lane writes 4 consecutive k (b64)
#pragma unroll
    for (int nq = 0; nq < 2; ++nq)
#pragma unroll
      for (int mt = 0; mt < 4; ++mt) {
        bf16x4 p4 = {(__bf16)sacc[nq][mt][0], (__bf16)sacc[nq][mt][1],
                     (__bf16)sacc[nq][mt][2], (__bf16)sacc[nq][mt][3]};
        *(bf16x4*)(&Ps[w][nq * 16 + l15][mt * 16 + lq * 4]) = p4;
      }
    __threadfence_block();  // wave-private P round-trip

    // O^T += Vt · P
    __builtin_amdgcn_s_setprio(1);
#pragma unroll
    for (int s = 0; s < 2; ++s) {
      bf16x8 bp[2];
#pragma unroll
      for (int nq = 0; nq < 2; ++nq)
        bp[nq] = *(const bf16x8*)(&Ps[w][nq * 16 + l15][s * 32 + lq * 8]);
#pragma unroll
      for (int mt = 0; mt < 4; ++mt) {
        bf16x8 av = *(const bf16x8*)(&Vs[sl][mt * 16 + l15][((s * 4 + lq) ^ xs) * 8]);
#pragma unroll
        for (int nq = 0; nq < 2; ++nq)
          oacc[nq][mt] = __builtin_amdgcn_mfma_f32_16x16x32_bf16(
              av, bp[nq], oacc[nq][mt], 0, 0, 0);
      }
    }
    __builtin_amdgcn_s_setprio(0);
    // no trailing barrier: next-iter vmcnt+s_barrier protects ring reuse
  }

  // epilogue: O^T col=q(l15), row=d=mt*16+lq*4+r; write O[b*1024+q][h*64+d]
  const int b = bh >> 4, h = bh & 15;
#pragma unroll
  for (int nq = 0; nq < 2; ++nq) {
    const float inv = 1.0f / (l_run[nq] * 32.0f);
    const size_t base =
        (size_t)(b * 1024 + qt * 128 + w * 32 + nq * 16 + l15) * 1024 + h * 64;
#pragma unroll
    for (int mt = 0; mt < 4; ++mt) {
      bf16x4 o4 = {(__bf16)(oacc[nq][mt][0] * inv), (__bf16)(oacc[nq][mt][1] * inv),
                   (__bf16)(oacc[nq][mt][2] * inv), (__bf16)(oacc[nq][mt][3] * inv)};
      *(bf16x4*)(&O[base + mt * 16 + lq * 4]) = o4;
    }
  }
}

// ---------------------------------------------------------------------------
extern "C" void kernel_launch(void* const* d_in, const int* in_sizes, int n_in,
                              void* d_out, int out_size, void* d_ws, size_t ws_size,
                              hipStream_t stream) {
  const float* x  = (const float*)d_in[0];
  const float* Wq = (const float*)d_in[1];
  const float* bq = (const float*)d_in[2];
  const float* Wk = (const float*)d_in[3];
  const float* bk = (const float*)d_in[4];
  const float* Wv = (const float*)d_in[5];
  const float* bv = (const float*)d_in[6];
  const float* Wo = (const float*)d_in[7];
  const float* bo = (const float*)d_in[8];
  float* out = (float*)d_out;

  const size_t SZ = (size_t)4 * 1024 * 1024;  // 4M bf16 per slot (8 MB)
  __bf16* Qw = (__bf16*)d_ws;
  __bf16* Kw = Qw + SZ;
  __bf16* Vw = Kw + SZ;
  __bf16* s3 = Vw + SZ;  // xb during QKV, then Ow
  __bf16* xb = s3;
  __bf16* Ow = s3;

  dim3 blk(256);

  static bool attr_set = false;
  if (!attr_set) {
    (void)hipFuncSetAttribute((const void*)gemm_qkv9,
                              hipFuncAttributeMaxDynamicSharedMemorySize, 139264);
    (void)hipFuncSetAttribute((const void*)attn_kernel,
                              hipFuncAttributeMaxDynamicSharedMemorySize, 67584);
    (void)hipFuncSetAttribute((const void*)gemm_out,
                              hipFuncAttributeMaxDynamicSharedMemorySize, 73728);
    attr_set = true;
  }

  if (ws_size >= (size_t)40 * 1024 * 1024) {
    __bf16* Wqb = s3 + SZ;  // 2 MB each
    __bf16* Wkb = Wqb + SZ / 4;
    __bf16* Wvb = Wkb + SZ / 4;
    __bf16* Wob = Wvb + SZ / 4;
    cvt_all<<<8192, blk, 0, stream>>>(x, Wq, Wk, Wv, Wo, xb, Wqb, Wkb, Wvb, Wob);
    gemm_qkv9<<<dim3(256), dim3(512), 139264, stream>>>(xb, Wqb, Wkb, Wvb,
                                                        bq, bk, bv, Qw, Kw, Vw);
    attn_kernel<<<dim3(64, 8), blk, 67584, stream>>>(Qw, Kw, Vw, Ow);
    gemm_out<<<dim3(512), blk, 73728, stream>>>(Ow, Wob, bo, out);
  } else {
    __bf16* Wob = Kw;  // Kw dead after attention
    cvt_f32_bf16<<<4096, blk, 0, stream>>>(x, xb, 1048576);
    gemm_qkv<false><<<dim3(768), blk, 0, stream>>>(xb, Wq, Wk, Wv,
                                                   bq, bk, bv, Qw, Kw, Vw);
    attn_kernel<<<dim3(64, 8), blk, 67584, stream>>>(Qw, Kw, Vw, Ow);
    cvt_f32_bf16<<<1024, blk, 0, stream>>>(Wo, Wob, 262144);
    gemm_out<<<dim3(512), blk, 73728, stream>>>(Ow, Wob, bo, out);
  }
}

// Round 7
// 163.299 us; speedup vs baseline: 1.1606x; 1.1606x over previous
//
#include <hip/hip_runtime.h>
#include <hip/hip_bf16.h>

// MHA: B=4, N=1024, E=1024, H=16, d=64.  fp32 I/O, bf16 MFMA internals.
//
// Round 19: REVERT to round-5 best (158.9 us).  gemm_qkv9 (256x192 deep
// pipeline) regressed 2x: 9 barriers/K-step x 12-MFMA phases at 1 block/CU
// (no cross-block overlap to hide barrier latency).  Restored: r13 gemm_qkv
// (128x128, 3 blocks/CU, ~830 TF = its structure's ceiling), r17 ring-3
// counted-vmcnt attn + gemm_out, cvt_all.
//
// XOR-swizzled [row][64] LDS tiles: LDS[row][c8] holds G[row][c8 ^ (row&7)];
// frag readers XOR with l15&7.  Staging via global_load_lds(16B).
//
// ws (40 MB fast path): [Qw 8M][Kw 8M][Vw 8M][xb/Ow 8M][Wqb][Wkb][Wvb][Wob]
// (2 MB each).  ws_size < 40 MB -> fp32-W fallback (deterministic branch).
//
// MFMA m89/m91 layouts: A-frag A[m=l&15][k=(l>>4)*8+j]; B-frag same addressing
// from row-major [n][k]; C/D col=l&15, row=(l>>4)*4+reg.

typedef __bf16 bf16x8 __attribute__((ext_vector_type(8)));
typedef __bf16 bf16x4 __attribute__((ext_vector_type(4)));
typedef float  f32x4  __attribute__((ext_vector_type(4)));

#define LOG2E 1.44269504f

__device__ __forceinline__ void glds16(const __bf16* g, __bf16* l) {
  __builtin_amdgcn_global_load_lds(
      (const __attribute__((address_space(1))) void*)g,
      (__attribute__((address_space(3))) void*)l, 16, 0, 0);
}

__global__ __launch_bounds__(256) void cvt_f32_bf16(const float* __restrict__ in,
                                                    __bf16* __restrict__ out, int n4) {
  int i = blockIdx.x * 256 + threadIdx.x;
  if (i < n4) {
    float4 v = *(const float4*)(in + (size_t)i * 4);
    bf16x4 b = {(__bf16)v.x, (__bf16)v.y, (__bf16)v.z, (__bf16)v.w};
    *(bf16x4*)(out + (size_t)i * 4) = b;
  }
}

// Fused conversion: x (1M float4) + Wq/Wk/Wv/Wo (256K float4 each).
__global__ __launch_bounds__(256) void cvt_all(const float* __restrict__ x,
                                               const float* __restrict__ Wq,
                                               const float* __restrict__ Wk,
                                               const float* __restrict__ Wv,
                                               const float* __restrict__ Wo,
                                               __bf16* __restrict__ xb,
                                               __bf16* __restrict__ Wqb,
                                               __bf16* __restrict__ Wkb,
                                               __bf16* __restrict__ Wvb,
                                               __bf16* __restrict__ Wob) {
  const int i = blockIdx.x * 256 + threadIdx.x;  // 0..2097151
  const float* src;
  __bf16* dst;
  int off;
  if (i < 1048576) {
    src = x; dst = xb; off = i;
  } else {
    const int j = i - 1048576;
    const int seg = j >> 18;  // 0..3
    off = j & 262143;
    src = (seg == 0) ? Wq : (seg == 1) ? Wk : (seg == 2) ? Wv : Wo;
    dst = (seg == 0) ? Wqb : (seg == 1) ? Wkb : (seg == 2) ? Wvb : Wob;
  }
  float4 v = *(const float4*)(src + (size_t)off * 4);
  bf16x4 b = {(__bf16)v.x, (__bf16)v.y, (__bf16)v.z, (__bf16)v.w};
  *(bf16x4*)(dst + (size_t)off * 4) = b;
}

// ---------------------------------------------------------------------------
// Fused QKV projection, 128x128 tile, BK=64, 1D grid 768 (3 blocks/CU).
// XCD decomposition: c=bid&7 -> XCD c owns m-blocks c*4..c*4+3 for all z,nb.
// z=0/1/2 -> Q/K (head layout [b,h,n,d]), V (transposed [b,h,d,n]).
// Q epilogue scaled by log2(e) so attn can use exp2 directly.
// ---------------------------------------------------------------------------
template <bool WBF16>
__global__ __launch_bounds__(256, 3) void gemm_qkv(const __bf16* __restrict__ A,
                                                   const void* __restrict__ Wqp,
                                                   const void* __restrict__ Wkp,
                                                   const void* __restrict__ Wvp,
                                                   const float* __restrict__ bq,
                                                   const float* __restrict__ bk,
                                                   const float* __restrict__ bv,
                                                   __bf16* __restrict__ Qw,
                                                   __bf16* __restrict__ Kw,
                                                   __bf16* __restrict__ Vw) {
  constexpr int BST = WBF16 ? 64 : 72;
  __shared__ __attribute__((aligned(16))) __bf16 As[128][64];
  __shared__ __attribute__((aligned(16))) __bf16 Bs[128 * BST];

  const int tid = threadIdx.x;
  const int lane = tid & 63, w = tid >> 6;
  const int wm = w >> 1, wn = w & 1;
  const int l15 = lane & 15, lq = lane >> 4;
  const int lr = lane >> 3, lc = lane & 7;
  const int xs = l15 & 7;

  const int bid = blockIdx.x;
  const int c = bid & 7, t = bid >> 3;
  const int z = t >> 5;
  const int r = t & 31;
  const int nb = r & 7;
  const int mb = c * 4 + (r >> 3);
  const int m0 = mb * 128, n0 = nb * 128;

  const void* Wp = (z == 0) ? Wqp : (z == 1) ? Wkp : Wvp;
  const float* bias = (z == 0) ? bq : (z == 1) ? bk : bv;
  __bf16* C = (z == 0) ? Qw : (z == 1) ? Kw : Vw;
  const float scale = (z == 0) ? LOG2E : 1.0f;

  f32x4 acc[4][4] = {};

  for (int k0 = 0; k0 < 1024; k0 += 64) {
#pragma unroll
    for (int i = 0; i < 4; ++i) {
      const int row = w * 32 + i * 8 + lr;
      glds16(A + (size_t)(m0 + row) * 1024 + k0 + ((lc ^ lr) * 8), &As[row][lc * 8]);
    }
    if (WBF16) {
      const __bf16* Wb = (const __bf16*)Wp;
#pragma unroll
      for (int i = 0; i < 4; ++i) {
        const int row = w * 32 + i * 8 + lr;
        glds16(Wb + (size_t)(n0 + row) * 1024 + k0 + ((lc ^ lr) * 8), &Bs[row * 64 + lc * 8]);
      }
    } else {
      const float* W = (const float*)Wp;
#pragma unroll
      for (int i = 0; i < 8; ++i) {
        const int cc = i * 256 + tid, row = cc >> 4, col = (cc & 15) * 4;
        float4 wv = *(const float4*)(W + (size_t)(n0 + row) * 1024 + k0 + col);
        bf16x4 b4 = {(__bf16)wv.x, (__bf16)wv.y, (__bf16)wv.z, (__bf16)wv.w};
        *(bf16x4*)(&Bs[row * 72 + col]) = b4;
      }
    }
    __syncthreads();
#pragma unroll
    for (int s = 0; s < 2; ++s) {
      bf16x8 af[4], bfv[4];
#pragma unroll
      for (int mt = 0; mt < 4; ++mt)
        af[mt] = *(const bf16x8*)(&As[wm * 64 + mt * 16 + l15][((s * 4 + lq) ^ xs) * 8]);
#pragma unroll
      for (int nt = 0; nt < 4; ++nt) {
        const int row = wn * 64 + nt * 16 + l15;
        if (WBF16)
          bfv[nt] = *(const bf16x8*)(&Bs[row * 64 + (((s * 4 + lq) ^ xs) * 8)]);
        else
          bfv[nt] = *(const bf16x8*)(&Bs[row * 72 + s * 32 + lq * 8]);
      }
#pragma unroll
      for (int mt = 0; mt < 4; ++mt)
#pragma unroll
        for (int nt = 0; nt < 4; ++nt)
          acc[mt][nt] = __builtin_amdgcn_mfma_f32_16x16x32_bf16(
              af[mt], bfv[nt], acc[mt][nt], 0, 0, 0);
    }
    __syncthreads();
  }

#pragma unroll
  for (int mt = 0; mt < 4; ++mt) {
    const int mg_base = m0 + wm * 64 + mt * 16 + lq * 4;
    const int bb = mg_base >> 10, nr0 = mg_base & 1023;
#pragma unroll
    for (int nt = 0; nt < 4; ++nt) {
      const int ng = n0 + wn * 64 + nt * 16 + l15;
      const float bv = bias[ng];
      const int h = ng >> 6, dd = ng & 63;
      if (z != 2) {
#pragma unroll
        for (int rr = 0; rr < 4; ++rr) {
          const int mg = mg_base + rr;
          const size_t idx =
              ((size_t)(bb * 16 + h) << 16) + (size_t)(mg & 1023) * 64 + dd;
          C[idx] = (__bf16)((acc[mt][nt][rr] + bv) * scale);
        }
      } else {
        bf16x4 o4 = {(__bf16)(acc[mt][nt][0] + bv), (__bf16)(acc[mt][nt][1] + bv),
                     (__bf16)(acc[mt][nt][2] + bv), (__bf16)(acc[mt][nt][3] + bv)};
        *(bf16x4*)(&C[((size_t)(bb * 16 + h) << 16) + (size_t)dd * 1024 + nr0]) = o4;
      }
    }
  }
}

// ---------------------------------------------------------------------------
// Out projection: out[4096,1024] fp32 = O @ Wo^T + bo.  64x128 tile, BK=64,
// 1D grid 512, XCD-mapped.  Ring-3 prefetch-distance-2, counted vmcnt:
// top of iter kb: vmcnt(6) [slot kb landed; kb+1,kb+2 in flight] -> s_barrier
// [slot (kb+2)%3 free] -> issue slot kb+2 -> compute slot kb.  6 glds/slot
// per wave (A 2 + B 4).  Dynamic LDS 72 KB (3 x (A 8K + B 16K)) -> 2/CU.
// ---------------------------------------------------------------------------
__global__ __launch_bounds__(256, 2) void gemm_out(const __bf16* __restrict__ A,
                                                   const __bf16* __restrict__ W,
                                                   const float* __restrict__ bias,
                                                   float* __restrict__ C) {
  extern __shared__ __attribute__((aligned(16))) __bf16 lds_o[];
  __bf16(*As)[64][64] = (__bf16(*)[64][64])lds_o;              // 3 x 4096
  __bf16(*Bs)[128][64] = (__bf16(*)[128][64])(lds_o + 12288);  // 3 x 8192

  const int tid = threadIdx.x;
  const int lane = tid & 63, w = tid >> 6;
  const int wm = w >> 1, wn = w & 1;
  const int l15 = lane & 15, lq = lane >> 4;
  const int lr = lane >> 3, lc = lane & 7;
  const int xs = l15 & 7;

  const int bid = blockIdx.x;
  const int c = bid & 7, t = bid >> 3;  // c = XCD, t = 0..63
  const int mb = c * 8 + (t & 7);       // 0..63
  const int nb = t >> 3;                // 0..7
  const int m0 = mb * 64, n0 = nb * 128;

  auto stage = [&](int kb, int sl) {
    const int k0 = kb * 64;
#pragma unroll
    for (int i = 0; i < 2; ++i) {  // A: wave w rows w*16..+15
      const int row = w * 16 + i * 8 + lr;
      glds16(A + (size_t)(m0 + row) * 1024 + k0 + ((lc ^ lr) * 8), &As[sl][row][lc * 8]);
    }
#pragma unroll
    for (int i = 0; i < 4; ++i) {  // B: wave w rows w*32..+31
      const int row = w * 32 + i * 8 + lr;
      glds16(W + (size_t)(n0 + row) * 1024 + k0 + ((lc ^ lr) * 8), &Bs[sl][row][lc * 8]);
    }
  };

  f32x4 acc[2][4] = {};

  stage(0, 0);
  stage(1, 1);

  for (int kb = 0; kb < 16; ++kb) {
    if (kb < 15)
      asm volatile("s_waitcnt vmcnt(6)" ::: "memory");
    else
      asm volatile("s_waitcnt vmcnt(0)" ::: "memory");
    __builtin_amdgcn_s_barrier();
    if (kb < 14) stage(kb + 2, (kb + 2) % 3);

    const int sl = kb % 3;
#pragma unroll
    for (int s = 0; s < 2; ++s) {
      bf16x8 af[2], bfv[4];
#pragma unroll
      for (int mt = 0; mt < 2; ++mt)
        af[mt] = *(const bf16x8*)(&As[sl][wm * 32 + mt * 16 + l15][((s * 4 + lq) ^ xs) * 8]);
#pragma unroll
      for (int nt = 0; nt < 4; ++nt)
        bfv[nt] = *(const bf16x8*)(&Bs[sl][wn * 64 + nt * 16 + l15][((s * 4 + lq) ^ xs) * 8]);
      __builtin_amdgcn_s_setprio(1);
#pragma unroll
      for (int mt = 0; mt < 2; ++mt)
#pragma unroll
        for (int nt = 0; nt < 4; ++nt)
          acc[mt][nt] = __builtin_amdgcn_mfma_f32_16x16x32_bf16(
              af[mt], bfv[nt], acc[mt][nt], 0, 0, 0);
      __builtin_amdgcn_s_setprio(0);
    }
  }

#pragma unroll
  for (int mt = 0; mt < 2; ++mt) {
    const int mg_base = m0 + wm * 32 + mt * 16 + lq * 4;
#pragma unroll
    for (int nt = 0; nt < 4; ++nt) {
      const int ng = n0 + wn * 64 + nt * 16 + l15;
      const float bv = bias[ng];
#pragma unroll
      for (int r = 0; r < 4; ++r)
        C[(size_t)(mg_base + r) * 1024 + ng] = acc[mt][nt][r] + bv;
    }
  }
}

// ---------------------------------------------------------------------------
// Flash attention, S^T orientation, 32 q per wave (128 q per block, grid
// (bh=64, qt=8) = 512 blocks = 2/CU).  Ring-3 prefetch-distance-2 K/V with
// counted vmcnt: top of iter kb: vmcnt(4) [slot kb landed; kb+1,kb+2 in
// flight] -> s_barrier -> issue slot kb+2 -> compute slot kb.  4 glds/slot
// per wave (K 2 + V 2).  Q fragments register-hoisted; Q-stage LDS reused as
// P buffer.  Q pre-scaled by log2(e) -> exp2 softmax.  Reference divides by
// sqrt(E)=32 AFTER softmax -> /(l*32).  Dynamic LDS 66 KB -> 2/CU.
// ---------------------------------------------------------------------------
__global__ __launch_bounds__(256, 2) void attn_kernel(const __bf16* __restrict__ Q,
                                                      const __bf16* __restrict__ K,
                                                      const __bf16* __restrict__ Vt,
                                                      __bf16* __restrict__ O) {
  extern __shared__ __attribute__((aligned(16))) __bf16 lds_a[];
  __bf16(*Ks)[64][64] = (__bf16(*)[64][64])lds_a;               // 3 x 4096
  __bf16(*Vs)[64][64] = (__bf16(*)[64][64])(lds_a + 12288);     // 3 x 4096
  __bf16* PQ = lds_a + 24576;                                   // 9216 elems
  __bf16(*Qst)[64] = (__bf16(*)[64])PQ;                         // [128][64]
  __bf16(*Ps)[32][72] = (__bf16(*)[32][72])PQ;                  // [4][32][72]

  const int tid = threadIdx.x;
  const int lane = tid & 63, w = tid >> 6;
  const int l15 = lane & 15, lq = lane >> 4;
  const int lr = lane >> 3, lc = lane & 7;
  const int xs = l15 & 7;

  const int bh = blockIdx.x;  // 0..63  (same-head blocks share an XCD)
  const int qt = blockIdx.y;  // 0..7
  const __bf16* Qh = Q + (size_t)bh * 65536;
  const __bf16* Kh = K + (size_t)bh * 65536;
  const __bf16* Vh = Vt + (size_t)bh * 65536;

  auto stage_kv = [&](int kb, int sl) {
#pragma unroll
    for (int i = 0; i < 2; ++i) {
      const int row = w * 16 + i * 8 + lr;
      glds16(Kh + (size_t)kb * 4096 + (size_t)row * 64 + ((lc ^ lr) * 8),
             &Ks[sl][row][lc * 8]);
      glds16(Vh + (size_t)row * 1024 + kb * 64 + ((lc ^ lr) * 8),
             &Vs[sl][row][lc * 8]);
    }
  };

  // prologue: stage Q tile (128x64) + K/V slot 0
#pragma unroll
  for (int i = 0; i < 4; ++i) {
    const int row = w * 32 + i * 8 + lr;
    glds16(Qh + (size_t)(qt * 128 + row) * 64 + ((lc ^ lr) * 8), &Qst[row][lc * 8]);
  }
  stage_kv(0, 0);
  __syncthreads();  // drain Q + slot0 glds for all waves
  bf16x8 bqr[2][2];  // [nq][s]
#pragma unroll
  for (int nq = 0; nq < 2; ++nq)
#pragma unroll
    for (int s = 0; s < 2; ++s)
      bqr[nq][s] = *(const bf16x8*)(&Qst[w * 32 + nq * 16 + l15][((s * 4 + lq) ^ xs) * 8]);
  __syncthreads();  // all waves done reading Qst before PQ reused as Ps
  stage_kv(1, 1);   // distance-2 pipeline primed (4 loads in flight)

  float l_run[2] = {0.0f, 0.0f};
  f32x4 oacc[2][4] = {};

  for (int kb = 0; kb < 16; ++kb) {
    if (kb < 15)
      asm volatile("s_waitcnt vmcnt(4)" ::: "memory");
    else
      asm volatile("s_waitcnt vmcnt(0)" ::: "memory");
    __builtin_amdgcn_s_barrier();
    if (kb < 14) stage_kv(kb + 2, (kb + 2) % 3);
    const int sl = kb % 3;

    // S^T: rows = kseq(64), cols = this wave's 32 q (2 frags of 16)
    f32x4 sacc[2][4] = {};
    __builtin_amdgcn_s_setprio(1);
#pragma unroll
    for (int s = 0; s < 2; ++s) {
#pragma unroll
      for (int mt = 0; mt < 4; ++mt) {
        bf16x8 ak = *(const bf16x8*)(&Ks[sl][mt * 16 + l15][((s * 4 + lq) ^ xs) * 8]);
#pragma unroll
        for (int nq = 0; nq < 2; ++nq)
          sacc[nq][mt] = __builtin_amdgcn_mfma_f32_16x16x32_bf16(
              ak, bqr[nq][s], sacc[nq][mt], 0, 0, 0);
      }
    }
    __builtin_amdgcn_s_setprio(0);

    // softmax numerator via exp2 (per-lane q = w*32 + nq*16 + l15)
#pragma unroll
    for (int nq = 0; nq < 2; ++nq) {
      float sum = 0.0f;
#pragma unroll
      for (int mt = 0; mt < 4; ++mt)
#pragma unroll
        for (int r = 0; r < 4; ++r) {
          const float e = __builtin_amdgcn_exp2f(sacc[nq][mt][r]);
          sacc[nq][mt][r] = e;
          sum += e;
        }
      sum += __shfl_xor(sum, 16, 64);
      sum += __shfl_xor(sum, 32, 64);
      l_run[nq] += sum;
    }

    // P -> LDS row-major [q][k] (padded), lane writes 4 consecutive k (b64)
#pragma unroll
    for (int nq = 0; nq < 2; ++nq)
#pragma unroll
      for (int mt = 0; mt < 4; ++mt) {
        bf16x4 p4 = {(__bf16)sacc[nq][mt][0], (__bf16)sacc[nq][mt][1],
                     (__bf16)sacc[nq][mt][2], (__bf16)sacc[nq][mt][3]};
        *(bf16x4*)(&Ps[w][nq * 16 + l15][mt * 16 + lq * 4]) = p4;
      }
    __threadfence_block();  // wave-private P round-trip

    // O^T += Vt · P
    __builtin_amdgcn_s_setprio(1);
#pragma unroll
    for (int s = 0; s < 2; ++s) {
      bf16x8 bp[2];
#pragma unroll
      for (int nq = 0; nq < 2; ++nq)
        bp[nq] = *(const bf16x8*)(&Ps[w][nq * 16 + l15][s * 32 + lq * 8]);
#pragma unroll
      for (int mt = 0; mt < 4; ++mt) {
        bf16x8 av = *(const bf16x8*)(&Vs[sl][mt * 16 + l15][((s * 4 + lq) ^ xs) * 8]);
#pragma unroll
        for (int nq = 0; nq < 2; ++nq)
          oacc[nq][mt] = __builtin_amdgcn_mfma_f32_16x16x32_bf16(
              av, bp[nq], oacc[nq][mt], 0, 0, 0);
      }
    }
    __builtin_amdgcn_s_setprio(0);
    // no trailing barrier: next-iter vmcnt+s_barrier protects ring reuse
  }

  // epilogue: O^T col=q(l15), row=d=mt*16+lq*4+r; write O[b*1024+q][h*64+d]
  const int b = bh >> 4, h = bh & 15;
#pragma unroll
  for (int nq = 0; nq < 2; ++nq) {
    const float inv = 1.0f / (l_run[nq] * 32.0f);
    const size_t base =
        (size_t)(b * 1024 + qt * 128 + w * 32 + nq * 16 + l15) * 1024 + h * 64;
#pragma unroll
    for (int mt = 0; mt < 4; ++mt) {
      bf16x4 o4 = {(__bf16)(oacc[nq][mt][0] * inv), (__bf16)(oacc[nq][mt][1] * inv),
                   (__bf16)(oacc[nq][mt][2] * inv), (__bf16)(oacc[nq][mt][3] * inv)};
      *(bf16x4*)(&O[base + mt * 16 + lq * 4]) = o4;
    }
  }
}

// ---------------------------------------------------------------------------
extern "C" void kernel_launch(void* const* d_in, const int* in_sizes, int n_in,
                              void* d_out, int out_size, void* d_ws, size_t ws_size,
                              hipStream_t stream) {
  const float* x  = (const float*)d_in[0];
  const float* Wq = (const float*)d_in[1];
  const float* bq = (const float*)d_in[2];
  const float* Wk = (const float*)d_in[3];
  const float* bk = (const float*)d_in[4];
  const float* Wv = (const float*)d_in[5];
  const float* bv = (const float*)d_in[6];
  const float* Wo = (const float*)d_in[7];
  const float* bo = (const float*)d_in[8];
  float* out = (float*)d_out;

  const size_t SZ = (size_t)4 * 1024 * 1024;  // 4M bf16 per slot (8 MB)
  __bf16* Qw = (__bf16*)d_ws;
  __bf16* Kw = Qw + SZ;
  __bf16* Vw = Kw + SZ;
  __bf16* s3 = Vw + SZ;  // xb during QKV, then Ow
  __bf16* xb = s3;
  __bf16* Ow = s3;

  dim3 blk(256);

  static bool attr_set = false;
  if (!attr_set) {
    (void)hipFuncSetAttribute((const void*)attn_kernel,
                              hipFuncAttributeMaxDynamicSharedMemorySize, 67584);
    (void)hipFuncSetAttribute((const void*)gemm_out,
                              hipFuncAttributeMaxDynamicSharedMemorySize, 73728);
    attr_set = true;
  }

  if (ws_size >= (size_t)40 * 1024 * 1024) {
    __bf16* Wqb = s3 + SZ;  // 2 MB each
    __bf16* Wkb = Wqb + SZ / 4;
    __bf16* Wvb = Wkb + SZ / 4;
    __bf16* Wob = Wvb + SZ / 4;
    cvt_all<<<8192, blk, 0, stream>>>(x, Wq, Wk, Wv, Wo, xb, Wqb, Wkb, Wvb, Wob);
    gemm_qkv<true><<<dim3(768), blk, 0, stream>>>(xb, Wqb, Wkb, Wvb,
                                                  bq, bk, bv, Qw, Kw, Vw);
    attn_kernel<<<dim3(64, 8), blk, 67584, stream>>>(Qw, Kw, Vw, Ow);
    gemm_out<<<dim3(512), blk, 73728, stream>>>(Ow, Wob, bo, out);
  } else {
    __bf16* Wob = Kw;  // Kw dead after attention
    cvt_f32_bf16<<<4096, blk, 0, stream>>>(x, xb, 1048576);
    gemm_qkv<false><<<dim3(768), blk, 0, stream>>>(xb, Wq, Wk, Wv,
                                                   bq, bk, bv, Qw, Kw, Vw);
    attn_kernel<<<dim3(64, 8), blk, 67584, stream>>>(Qw, Kw, Vw, Ow);
    cvt_f32_bf16<<<1024, blk, 0, stream>>>(Wo, Wob, 262144);
    gemm_out<<<dim3(512), blk, 73728, stream>>>(Ow, Wob, bo, out);
  }
}